// Round 2
// 514.245 us; speedup vs baseline: 1.3098x; 1.3098x over previous
//
#include <hip/hip_runtime.h>

// GAT encoder, fused: B=8192 graphs (1024 scenes x 8 steps), N=64 nodes, F=64.
// One 256-thread block per graph. fp32 (no fp32 MFMA on CDNA4).
//
// LDS = 53248 B (= 104 * 512) -> 3 blocks/CU (was 56320 -> 2 blocks/CU).
// Pad columns of h/hp carry the small vectors so no extra arrays are needed:
//   h[n][64] = mask, h[n][65] = a_src, h[n][66] = a_dst
//   hp[n][64] = b1,  hp[o][65] = b0 (o<16)
// red[0..3] = per-group masked sum  / mean+rstd after combine
// red[4..7] = per-group masked sumsq / per-head masked dst-scores (darr)
//
// Softmax without row-max: visible-pair scores are O(30) << 88, exp can't
// overflow on the live path. Masked m: darr = -1e30 -> exp underflows to 0
// (matches ref's exp(NEG - max) == 0). Fully-masked row <=> mask[n]==0:
// e = fma(exp, mask_n, 1-mask_n) -> uniform 1/64 as in the reference.
// NaN guard (round-1 lesson): invisible rows have UNNORMALIZED-scale scores
// (|v| can be ~1e5 since their h isn't mask-protected); exp overflows to inf
// and inf*0 = NaN. Clamp v <= 87 before exp: bitwise-neutral for visible
// pairs, bounds exp finite so the *mask kills it exactly.

__global__ __launch_bounds__(256, 3) void gat_fused(
    const float* __restrict__ x, const int* __restrict__ fhi,
    const float* __restrict__ w0g, const float* __restrict__ as0,
    const float* __restrict__ ad0, const float* __restrict__ b0g,
    const float* __restrict__ w1g, const float* __restrict__ as1,
    const float* __restrict__ ad1, const float* __restrict__ b1g,
    float* __restrict__ out)
{
    const int b = blockIdx.x;
    const int scene = b >> 3;   // b / T
    const int tt = b & 7;       // b % T
    const int tid = threadIdx.x;

    __shared__ __align__(16) float h[64][68];    // 17408 B
    __shared__ __align__(16) float hp[64][68];   // 17408 B
    __shared__ __align__(16) float W[64][64];    // 16384 B
    __shared__ __align__(16) float red[8][64];   //  2048 B

    const int grp = tid >> 6, n = tid & 63;      // attn/score/norm mapping
    const int r0 = (tid >> 4) * 4;               // matmul: 4 rows ...
    const int c0 = (tid & 15) * 4;               //         x 4 cols per thread

    // ---------------- stage x, W0 (concat-transposed), small vectors ----------------
    {
        const float* xb = x + (size_t)b * 4096;
        #pragma unroll
        for (int k = 0; k < 4; ++k) {
            int idx = (k * 256 + tid) * 4;
            float4 v = *(const float4*)(xb + idx);
            *(float4*)&h[idx >> 6][idx & 63] = v;
        }
        #pragma unroll
        for (int k = 0; k < 4; ++k) {
            int idx = (k * 256 + tid) * 4;            // w0 is [4][64][16]
            float4 v = *(const float4*)(w0g + idx);
            int hh = idx >> 10, f = (idx >> 4) & 63, o = idx & 15;
            *(float4*)&W[f][hh * 16 + o] = v;         // W[f][head*16+o]
        }
        if (tid < 64) {
            h[tid][64] = (fhi[scene * 64 + tid] <= tt) ? 1.0f : 0.0f;
            h[tid][65] = as0[tid];
            h[tid][66] = ad0[tid];
            hp[tid][64] = b1g[tid];
            if (tid < 16) hp[tid][65] = b0g[tid];
        }
    }
    __syncthreads();

    // visible count (same for both layers) — register per tid<64
    float invcnt = 0.f;
    if (tid < 64) {
        float c = 0.f;
        #pragma unroll
        for (int m = 0; m < 64; ++m) c += h[m][64];
        invcnt = 1.0f / fmaxf(c, 1.0f);
    }

    // ---------------- masked instance norm, one-pass var (in place) ----------------
    auto do_norm = [&]() {
        float s = 0.f, q = 0.f;
        #pragma unroll
        for (int k = 0; k < 16; ++k) {
            int r = grp * 16 + k;
            float mv = h[r][64];
            float xv = h[r][n];
            float xm = xv * mv;
            s += xm;
            q = fmaf(xm, xv, q);
        }
        red[grp][n] = s;
        red[4 + grp][n] = q;
        __syncthreads();
        if (tid < 64) {
            float sum = red[0][tid] + red[1][tid] + red[2][tid] + red[3][tid];
            float ssq = red[4][tid] + red[5][tid] + red[6][tid] + red[7][tid];
            float mean = sum * invcnt;
            float var = fmaxf(ssq * invcnt - mean * mean, 0.f);
            red[0][tid] = mean;
            red[1][tid] = rsqrtf(var + 1e-5f);
        }
        __syncthreads();
        {
            float mean = red[0][n], rstd = red[1][n];
            #pragma unroll
            for (int k = 0; k < 16; ++k) {
                int r = k * 4 + grp;
                h[r][n] = (h[r][n] - mean) * rstd;
            }
        }
        __syncthreads();
    };

    // ---------------- hp = h @ W : 4x4 outputs/thread, 128 b128 reads ----------------
    auto do_matmul = [&]() {
        float acc[4][4];
        #pragma unroll
        for (int i = 0; i < 4; ++i)
            #pragma unroll
            for (int j = 0; j < 4; ++j) acc[i][j] = 0.f;
        #pragma unroll 4
        for (int f0 = 0; f0 < 64; f0 += 4) {
            float4 w0v = *(const float4*)&W[f0 + 0][c0];
            float4 w1v = *(const float4*)&W[f0 + 1][c0];
            float4 w2v = *(const float4*)&W[f0 + 2][c0];
            float4 w3v = *(const float4*)&W[f0 + 3][c0];
            #pragma unroll
            for (int i = 0; i < 4; ++i) {
                float4 hv = *(const float4*)&h[r0 + i][f0];
                acc[i][0] = fmaf(hv.x, w0v.x, acc[i][0]);
                acc[i][1] = fmaf(hv.x, w0v.y, acc[i][1]);
                acc[i][2] = fmaf(hv.x, w0v.z, acc[i][2]);
                acc[i][3] = fmaf(hv.x, w0v.w, acc[i][3]);
                acc[i][0] = fmaf(hv.y, w1v.x, acc[i][0]);
                acc[i][1] = fmaf(hv.y, w1v.y, acc[i][1]);
                acc[i][2] = fmaf(hv.y, w1v.z, acc[i][2]);
                acc[i][3] = fmaf(hv.y, w1v.w, acc[i][3]);
                acc[i][0] = fmaf(hv.z, w2v.x, acc[i][0]);
                acc[i][1] = fmaf(hv.z, w2v.y, acc[i][1]);
                acc[i][2] = fmaf(hv.z, w2v.z, acc[i][2]);
                acc[i][3] = fmaf(hv.z, w2v.w, acc[i][3]);
                acc[i][0] = fmaf(hv.w, w3v.x, acc[i][0]);
                acc[i][1] = fmaf(hv.w, w3v.y, acc[i][1]);
                acc[i][2] = fmaf(hv.w, w3v.z, acc[i][2]);
                acc[i][3] = fmaf(hv.w, w3v.w, acc[i][3]);
            }
        }
        #pragma unroll
        for (int i = 0; i < 4; ++i)
            *(float4*)&hp[r0 + i][c0] = make_float4(acc[i][0], acc[i][1], acc[i][2], acc[i][3]);
        __syncthreads();
    };

    // --------- attention + aggregate; single pass, no row-max; writes into h ---------
    auto do_attn = [&](const float* __restrict__ drow, float sv,
                       int layer) {
        const int cb = grp * 16;
        const float mymask = h[n][64];
        const float base = 1.0f - mymask;   // e==1 for all m when row fully masked
        float denom = 0.f;
        float acc[16];
        #pragma unroll
        for (int o = 0; o < 16; ++o) acc[o] = 0.f;
        #pragma unroll 4
        for (int m = 0; m < 64; ++m) {
            float v = sv + drow[m];                 // masked m: -1e30
            v = fmaxf(v, 0.2f * v);                 // leaky relu
            v = fminf(v, 87.f);                     // NaN guard (see header comment)
            float e = fmaf(__expf(v), mymask, base);// masked m -> exp==0 exactly
            denom += e;
            const float* hrow = &hp[m][cb];
            float4 p0 = *(const float4*)(hrow);
            float4 p1 = *(const float4*)(hrow + 4);
            float4 p2 = *(const float4*)(hrow + 8);
            float4 p3 = *(const float4*)(hrow + 12);
            acc[0]  = fmaf(e, p0.x, acc[0]);  acc[1]  = fmaf(e, p0.y, acc[1]);
            acc[2]  = fmaf(e, p0.z, acc[2]);  acc[3]  = fmaf(e, p0.w, acc[3]);
            acc[4]  = fmaf(e, p1.x, acc[4]);  acc[5]  = fmaf(e, p1.y, acc[5]);
            acc[6]  = fmaf(e, p1.z, acc[6]);  acc[7]  = fmaf(e, p1.w, acc[7]);
            acc[8]  = fmaf(e, p2.x, acc[8]);  acc[9]  = fmaf(e, p2.y, acc[9]);
            acc[10] = fmaf(e, p2.z, acc[10]); acc[11] = fmaf(e, p2.w, acc[11]);
            acc[12] = fmaf(e, p3.x, acc[12]); acc[13] = fmaf(e, p3.y, acc[13]);
            acc[14] = fmaf(e, p3.z, acc[14]); acc[15] = fmaf(e, p3.w, acc[15]);
        }
        float inv = 1.0f / denom;
        if (layer == 0) {
            #pragma unroll
            for (int o = 0; o < 16; ++o) {
                float res = fmaf(acc[o], inv, hp[o][65]);          // + b0
                res = (res > 0.f) ? res : (__expf(res) - 1.0f);    // ELU
                h[n][cb + o] = res;                                // concat heads
            }
        } else {
            #pragma unroll
            for (int o = 0; o < 16; ++o)
                h[n][cb + o] = fmaf(acc[o], inv, hp[cb + o][64]);  // + b1
        }
        __syncthreads();
    };

    // ================= layer 0 =================
    do_norm();
    do_matmul();
    float sv0;
    {   // per-head 16-dim score dots; fold mask into darr (masked -> -1e30)
        const int cb = grp * 16;
        float pv[16];
        *(float4*)&pv[0]  = *(const float4*)&hp[n][cb];
        *(float4*)&pv[4]  = *(const float4*)&hp[n][cb + 4];
        *(float4*)&pv[8]  = *(const float4*)&hp[n][cb + 8];
        *(float4*)&pv[12] = *(const float4*)&hp[n][cb + 12];
        float sv = 0.f, dv = 0.f;
        #pragma unroll
        for (int o = 0; o < 16; ++o) {
            sv = fmaf(pv[o], h[cb + o][65], sv);
            dv = fmaf(pv[o], h[cb + o][66], dv);
        }
        sv0 = sv;
        red[4 + grp][n] = (h[n][64] > 0.f) ? dv : -1e30f;
    }
    // stage W1 now (W dead until matmul L1) so HBM latency hides under attn0
    #pragma unroll
    for (int k = 0; k < 4; ++k) {
        int idx = (k * 256 + tid) * 4;
        float4 v = *(const float4*)(w1g + idx);
        *(float4*)&W[idx >> 6][idx & 63] = v;
    }
    __syncthreads();
    // a_src/a_dst for layer 1 (pads untouched by attn; consumed after its barrier)
    if (tid < 64) { h[tid][65] = as1[tid]; h[tid][66] = ad1[tid]; }
    do_attn(red[4 + grp], sv0, 0);   // h = elu(concat heads)

    // ================= layer 1 =================
    do_norm();
    do_matmul();
    float sv1;
    {   // single head, 64-dim dots; wave 1 also produces masked darr
        float sv = 0.f;
        #pragma unroll
        for (int o = 0; o < 64; o += 4) {
            float4 p = *(const float4*)&hp[n][o];
            sv = fmaf(p.x, h[o][65], sv);
            sv = fmaf(p.y, h[o + 1][65], sv);
            sv = fmaf(p.z, h[o + 2][65], sv);
            sv = fmaf(p.w, h[o + 3][65], sv);
        }
        sv1 = sv;
        if (grp == 1) {
            float dv = 0.f;
            #pragma unroll
            for (int o = 0; o < 64; o += 4) {
                float4 p = *(const float4*)&hp[n][o];
                dv = fmaf(p.x, h[o][66], dv);
                dv = fmaf(p.y, h[o + 1][66], dv);
                dv = fmaf(p.z, h[o + 2][66], dv);
                dv = fmaf(p.w, h[o + 3][66], dv);
            }
            red[4][n] = (h[n][64] > 0.f) ? dv : -1e30f;
        }
    }
    __syncthreads();
    do_attn(red[4], sv1, 1);         // h = out + b1

    // ---------------- coalesced store ----------------
    {
        float* ob = out + (size_t)b * 4096;
        #pragma unroll
        for (int k = 0; k < 4; ++k) {
            int idx = (k * 256 + tid) * 4;
            *(float4*)(ob + idx) = *(const float4*)&h[idx >> 6][idx & 63];
        }
    }
}

extern "C" void kernel_launch(void* const* d_in, const int* in_sizes, int n_in,
                              void* d_out, int out_size, void* d_ws, size_t ws_size,
                              hipStream_t stream)
{
    const float* x   = (const float*)d_in[0];
    const int*   fhi = (const int*)d_in[1];
    const float* w0  = (const float*)d_in[2];
    const float* as0 = (const float*)d_in[3];
    const float* ad0 = (const float*)d_in[4];
    const float* b0  = (const float*)d_in[5];
    const float* w1  = (const float*)d_in[6];
    const float* as1 = (const float*)d_in[7];
    const float* ad1 = (const float*)d_in[8];
    const float* b1  = (const float*)d_in[9];
    float* o = (float*)d_out;
    hipLaunchKernelGGL(gat_fused, dim3(8192), dim3(256), 0, stream,
                       x, fhi, w0, as0, ad0, b0, w1, as1, ad1, b1, o);
}

// Round 3
// 299.385 us; speedup vs baseline: 2.2498x; 1.7177x over previous
//
#include <hip/hip_runtime.h>

// GAT encoder, fused, bf16-MFMA version. B=8192 graphs, N=64 nodes, F=64.
// One 256-thread block (4 waves) per graph; 4 blocks/CU (LDS 33856 B).
//
// All four 64x64x64 matmuls (h@W per layer, P@hp per layer) run on
// v_mfma_f32_16x16x32_bf16. Norm stats, scores->exp softmax and denominators
// stay fp32. P (attention weights) is built in registers directly in MFMA
// A-fragment layout: lane l of wave w owns P[16w+(l&15)][(l>>4)*8+j], so no
// P matrix is materialized and layer-1 computes each exp exactly once.
//
// Fragment layouts (gfx950, 16x16x32 bf16; C/D verified per guide m89):
//   A[m][k]: m = lane&15, k = (lane>>4)*8 + j   (8 bf16 = 4 VGPRs)
//   B[k][n]: n = lane&15, k = (lane>>4)*8 + j   -> read from transposed [n][k]
//   C/D[r]:  col = lane&15, row = (lane>>4)*4 + r
// Hence W is staged transposed (wt[o][f]) and hp is written transposed
// (hpt[o][n]) straight from C-fragments (4 bf16 pack -> one b64 store).
//
// Softmax: no row-max (visible-pair scores O(30) << 88). Masked m: darr=-1e30
// -> exp underflows to 0. Fully-masked row (mask[n]==0): e = 1-mask + exp*mask
// = 1 for every m -> uniform 1/64, as in the reference. fmin(v,87) guards the
// invisible-row garbage path from inf*0=NaN (round-1 lesson).

typedef __attribute__((ext_vector_type(8))) short bf16x8;
typedef __attribute__((ext_vector_type(4))) float f32x4;

__device__ __forceinline__ unsigned short f2b(float f) {   // RNE f32->bf16
    unsigned u = __builtin_bit_cast(unsigned, f);
    u = (u + 0x7FFFu + ((u >> 16) & 1u)) >> 16;
    return (unsigned short)u;
}
__device__ __forceinline__ float b2f(unsigned short s) {
    unsigned u = ((unsigned)s) << 16;
    return __builtin_bit_cast(float, u);
}

__global__ __launch_bounds__(256, 4) void gat_fused(
    const float* __restrict__ x, const int* __restrict__ fhi,
    const float* __restrict__ w0g, const float* __restrict__ as0,
    const float* __restrict__ ad0, const float* __restrict__ b0g,
    const float* __restrict__ w1g, const float* __restrict__ as1,
    const float* __restrict__ ad1, const float* __restrict__ b1g,
    float* __restrict__ out)
{
    const int b = blockIdx.x;
    const int scene = b >> 3;
    const int tt = b & 7;
    const int tid = threadIdx.x;
    const int lane = tid & 63;
    const int wv = tid >> 6;       // wave id 0..3
    const int lg = lane >> 4;      // quad group 0..3
    const int li = lane & 15;

    // bf16 tiles, row stride 72 (144 B: 16B-aligned rows, rows advance 4 banks
    // -> 2-way max conflict on b128 fragment reads).
    __shared__ __align__(16) unsigned short hb [64][72];   // x / normed h / L0 out (9216 B)
    __shared__ __align__(16) unsigned short wt [64][72];   // W^T  [o][f]            (9216 B)
    __shared__ __align__(16) unsigned short hpt[64][72];   // hp^T [o][n]            (9216 B)
    __shared__ float sarr[4][64];   // per-head src scores
    __shared__ float darr[4][64];   // per-head dst scores (masked -> -1e30)
    __shared__ float denv[4][64];   // per-head 1/denominator
    __shared__ float red [8][64];   // norm reduction scratch
    __shared__ float maskv[64], asv[64], adv[64], b1v[64], b0v[16];

    // ---------------- stage x (bf16), W0^T (concat), small vectors ----------------
    {
        const float* xb = x + (size_t)b * 4096;
        #pragma unroll
        for (int k = 0; k < 4; ++k) {
            int idx = (k * 256 + tid) * 4;
            float4 v = *(const float4*)(xb + idx);
            int n = idx >> 6, c = idx & 63;
            ushort4 bv;
            bv.x = f2b(v.x); bv.y = f2b(v.y); bv.z = f2b(v.z); bv.w = f2b(v.w);
            *(ushort4*)&hb[n][c] = bv;
        }
        #pragma unroll
        for (int k = 0; k < 4; ++k) {
            int idx = (k * 256 + tid) * 4;           // w0 is [4][64][16]
            float4 v = *(const float4*)(w0g + idx);
            int hh = idx >> 10, f = (idx >> 4) & 63, o = idx & 15;
            wt[hh * 16 + o + 0][f] = f2b(v.x);
            wt[hh * 16 + o + 1][f] = f2b(v.y);
            wt[hh * 16 + o + 2][f] = f2b(v.z);
            wt[hh * 16 + o + 3][f] = f2b(v.w);
        }
        if (tid < 64) {
            maskv[tid] = (fhi[scene * 64 + tid] <= tt) ? 1.0f : 0.0f;
            asv[tid] = as0[tid];
            adv[tid] = ad0[tid];
            b1v[tid] = b1g[tid];
            if (tid < 16) b0v[tid] = b0g[tid];
        }
    }
    __syncthreads();

    float invcnt = 0.f;
    if (tid < 64) {
        float c = 0.f;
        #pragma unroll
        for (int m = 0; m < 64; ++m) c += maskv[m];
        invcnt = 1.0f / fmaxf(c, 1.0f);
    }

    // ---------------- masked instance norm on hb (bf16 in/out, fp32 stats) --------
    auto do_norm = [&]() {
        float s = 0.f, q = 0.f;
        #pragma unroll
        for (int k = 0; k < 16; ++k) {
            int r = k * 4 + wv;                     // interleaved rows: no wave skew
            float xv = b2f(hb[r][lane]);
            float xm = xv * maskv[r];
            s += xm;
            q = fmaf(xm, xv, q);
        }
        red[wv][lane] = s;
        red[4 + wv][lane] = q;
        __syncthreads();
        if (tid < 64) {
            float sum = red[0][tid] + red[1][tid] + red[2][tid] + red[3][tid];
            float ssq = red[4][tid] + red[5][tid] + red[6][tid] + red[7][tid];
            float mean = sum * invcnt;
            float var = fmaxf(ssq * invcnt - mean * mean, 0.f);
            red[0][tid] = mean;
            red[1][tid] = rsqrtf(var + 1e-5f);
        }
        __syncthreads();
        {
            float mean = red[0][lane], rstd = red[1][lane];
            #pragma unroll
            for (int k = 0; k < 16; ++k) {
                int r = k * 4 + wv;
                hb[r][lane] = f2b((b2f(hb[r][lane]) - mean) * rstd);
            }
        }
        __syncthreads();
    };

    // ---------------- hp = h @ W via MFMA; write hp^T bf16 ----------------
    auto do_matmul = [&]() {
        const unsigned short* arow = &hb[16 * wv + li][0];
        bf16x8 a0 = *(const bf16x8*)(arow + 8 * lg);
        bf16x8 a1 = *(const bf16x8*)(arow + 32 + 8 * lg);
        #pragma unroll
        for (int c = 0; c < 4; ++c) {
            const unsigned short* brow = &wt[16 * c + li][0];
            bf16x8 bv0 = *(const bf16x8*)(brow + 8 * lg);
            bf16x8 bv1 = *(const bf16x8*)(brow + 32 + 8 * lg);
            f32x4 acc = {0.f, 0.f, 0.f, 0.f};
            acc = __builtin_amdgcn_mfma_f32_16x16x32_bf16(a0, bv0, acc, 0, 0, 0);
            acc = __builtin_amdgcn_mfma_f32_16x16x32_bf16(a1, bv1, acc, 0, 0, 0);
            ushort4 pv;                              // rows 16wv+4lg+r, col 16c+li
            pv.x = f2b(acc[0]); pv.y = f2b(acc[1]);
            pv.z = f2b(acc[2]); pv.w = f2b(acc[3]);
            *(ushort4*)&hpt[16 * c + li][16 * wv + 4 * lg] = pv;
        }
        __syncthreads();
    };

    // ---------------- P (in-register, A-layout) + aggregate MFMA + epilogue -------
    auto do_attn = [&](int layer) {
        const int row = 16 * wv + li;               // this lane's P row
        const float mymask = maskv[row];
        const float base = 1.0f - mymask;
        const f32x4 zero = {0.f, 0.f, 0.f, 0.f};
        f32x4 C0 = zero, C1 = zero, C2 = zero, C3 = zero;
        float den[4] = {0.f, 0.f, 0.f, 0.f};

        if (layer == 0) {
            float sh[4];
            #pragma unroll
            for (int h = 0; h < 4; ++h) sh[h] = sarr[h][row];
            #pragma unroll
            for (int t = 0; t < 2; ++t) {
                const int mb = 32 * t + 8 * lg;     // k-offset this lane covers
                #pragma unroll
                for (int h = 0; h < 4; ++h) {
                    bf16x8 a;
                    #pragma unroll
                    for (int j = 0; j < 8; ++j) {
                        float v = sh[h] + darr[h][mb + j];
                        v = fmaxf(v, 0.2f * v);
                        v = fminf(v, 87.f);
                        float e = fmaf(__expf(v), mymask, base);
                        den[h] += e;
                        a[j] = (short)f2b(e);
                    }
                    bf16x8 bv = *(const bf16x8*)&hpt[16 * h + li][mb];
                    if (h == 0) C0 = __builtin_amdgcn_mfma_f32_16x16x32_bf16(a, bv, C0, 0, 0, 0);
                    if (h == 1) C1 = __builtin_amdgcn_mfma_f32_16x16x32_bf16(a, bv, C1, 0, 0, 0);
                    if (h == 2) C2 = __builtin_amdgcn_mfma_f32_16x16x32_bf16(a, bv, C2, 0, 0, 0);
                    if (h == 3) C3 = __builtin_amdgcn_mfma_f32_16x16x32_bf16(a, bv, C3, 0, 0, 0);
                }
            }
            #pragma unroll
            for (int h = 0; h < 4; ++h) {
                float d = den[h];
                d += __shfl_xor(d, 16);
                d += __shfl_xor(d, 32);
                denv[h][row] = 1.0f / d;
            }
            const int n0 = 16 * wv + 4 * lg;        // C-fragment rows
            #pragma unroll
            for (int c = 0; c < 4; ++c) {
                f32x4 C = (c == 0) ? C0 : (c == 1) ? C1 : (c == 2) ? C2 : C3;
                float bias = b0v[li];
                #pragma unroll
                for (int r = 0; r < 4; ++r) {
                    float val = fmaf(C[r], denv[c][n0 + r], bias);
                    val = (val > 0.f) ? val : (__expf(val) - 1.0f);   // ELU
                    hb[n0 + r][16 * c + li] = f2b(val);               // concat heads
                }
            }
            __syncthreads();
        } else {
            const float s0 = sarr[0][row];
            #pragma unroll
            for (int t = 0; t < 2; ++t) {
                const int mb = 32 * t + 8 * lg;
                bf16x8 a;
                #pragma unroll
                for (int j = 0; j < 8; ++j) {
                    float v = s0 + darr[0][mb + j];
                    v = fmaxf(v, 0.2f * v);
                    v = fminf(v, 87.f);
                    float e = fmaf(__expf(v), mymask, base);
                    den[0] += e;
                    a[j] = (short)f2b(e);
                }
                bf16x8 bv0 = *(const bf16x8*)&hpt[li][mb];
                bf16x8 bv1 = *(const bf16x8*)&hpt[16 + li][mb];
                bf16x8 bv2 = *(const bf16x8*)&hpt[32 + li][mb];
                bf16x8 bv3 = *(const bf16x8*)&hpt[48 + li][mb];
                C0 = __builtin_amdgcn_mfma_f32_16x16x32_bf16(a, bv0, C0, 0, 0, 0);
                C1 = __builtin_amdgcn_mfma_f32_16x16x32_bf16(a, bv1, C1, 0, 0, 0);
                C2 = __builtin_amdgcn_mfma_f32_16x16x32_bf16(a, bv2, C2, 0, 0, 0);
                C3 = __builtin_amdgcn_mfma_f32_16x16x32_bf16(a, bv3, C3, 0, 0, 0);
            }
            {
                float d = den[0];
                d += __shfl_xor(d, 16);
                d += __shfl_xor(d, 32);
                denv[0][row] = 1.0f / d;
            }
            const int n0 = 16 * wv + 4 * lg;
            float* ob = out + (size_t)b * 4096;
            #pragma unroll
            for (int c = 0; c < 4; ++c) {
                f32x4 C = (c == 0) ? C0 : (c == 1) ? C1 : (c == 2) ? C2 : C3;
                float bias = b1v[16 * c + li];
                #pragma unroll
                for (int r = 0; r < 4; ++r) {
                    float val = fmaf(C[r], denv[0][n0 + r], bias);
                    ob[(n0 + r) * 64 + 16 * c + li] = val;
                }
            }
        }
    };

    // ================= layer 0 =================
    do_norm();
    do_matmul();
    {   // per-head scores: wave h = wv, lane n
        float sv = 0.f, dv = 0.f;
        #pragma unroll
        for (int o = 0; o < 16; ++o) {
            float v = b2f(hpt[16 * wv + o][lane]);
            sv = fmaf(v, asv[16 * wv + o], sv);
            dv = fmaf(v, adv[16 * wv + o], dv);
        }
        sarr[wv][lane] = sv;
        darr[wv][lane] = (maskv[lane] > 0.f) ? dv : -1e30f;
    }
    __syncthreads();
    // stage W1^T + layer-1 a-vectors now (wt/asv dead until L1; latency hides
    // under attention's exp+MFMA work)
    #pragma unroll
    for (int k = 0; k < 4; ++k) {
        int idx = (k * 256 + tid) * 4;               // w1 is [64][64]
        float4 v = *(const float4*)(w1g + idx);
        int f = idx >> 6, o = idx & 63;
        wt[o + 0][f] = f2b(v.x);
        wt[o + 1][f] = f2b(v.y);
        wt[o + 2][f] = f2b(v.z);
        wt[o + 3][f] = f2b(v.w);
    }
    if (tid < 64) { asv[tid] = as1[tid]; adv[tid] = ad1[tid]; }
    do_attn(0);     // writes hb = elu(concat) and barriers

    // ================= layer 1 =================
    do_norm();
    do_matmul();
    if (tid < 128) {   // single head: wave0 -> s, wave1 -> d (64-dim dots)
        float acc = 0.f;
        const float* av = (tid < 64) ? asv : adv;
        #pragma unroll 8
        for (int o = 0; o < 64; ++o)
            acc = fmaf(b2f(hpt[o][lane]), av[o], acc);
        if (tid < 64) sarr[0][lane] = acc;
        else          darr[0][lane] = (maskv[lane] > 0.f) ? acc : -1e30f;
    }
    __syncthreads();
    do_attn(1);     // writes final output directly to global
}

extern "C" void kernel_launch(void* const* d_in, const int* in_sizes, int n_in,
                              void* d_out, int out_size, void* d_ws, size_t ws_size,
                              hipStream_t stream)
{
    const float* x   = (const float*)d_in[0];
    const int*   fhi = (const int*)d_in[1];
    const float* w0  = (const float*)d_in[2];
    const float* as0 = (const float*)d_in[3];
    const float* ad0 = (const float*)d_in[4];
    const float* b0  = (const float*)d_in[5];
    const float* w1  = (const float*)d_in[6];
    const float* as1 = (const float*)d_in[7];
    const float* ad1 = (const float*)d_in[8];
    const float* b1  = (const float*)d_in[9];
    float* o = (float*)d_out;
    hipLaunchKernelGGL(gat_fused, dim3(8192), dim3(256), 0, stream,
                       x, fhi, w0, as0, ad0, b0, w1, as1, ad1, b1, o);
}

// Round 4
// 286.476 us; speedup vs baseline: 2.3511x; 1.0451x over previous
//
#include <hip/hip_runtime.h>
#include <hip/hip_bf16.h>

// GAT encoder, fused, bf16-MFMA version. B=8192 graphs, N=64 nodes, F=64.
// One 256-thread block (4 waves) per graph; 5 blocks/CU (LDS 31808 B).
//
// R4 changes vs R3:
//  - prep_weights pre-kernel converts W0/W1 once to bf16, pre-transposed, in
//    d_ws; main blocks stage them with 16B copies (no per-block transpose).
//  - hardware bf16 converts (__float2bfloat16 -> v_cvt_pk_bf16_f32) replace
//    the 4-op manual RNE everywhere.
//  - scores are stored pre-scaled by log2(e) and clamped to 63 (live values
//    |s*log2e| <~ 30; clamp only guards invisible-row garbage; 63+63 < 128
//    keeps exp2 finite so the *mask kills it exactly). P-build inner loop is
//    add, lrelu(mul+max), exp2, mask-fma, denom-add, cvt.
//  - norm scratch red[8][64] aliases sarr/darr (disjoint live ranges):
//    LDS 34304 -> 31808 -> 5 blocks/CU.
//
// Fragment layouts (gfx950 16x16x32 bf16):
//   A[m][k]: m=lane&15, k=(lane>>4)*8+j ; B[k][n]: n=lane&15, same k
//   C/D[r]: col=lane&15, row=(lane>>4)*4+r
// W staged transposed (wt[o][f]); hp written transposed (hpt[o][n]).
// Bank note: wave-wide ds_read_b128 of fragments puts exactly 8 dwords on
// every bank (uniform) -> the 14M SQ_LDS_BANK_CONFLICT seen in R3 is the
// inherent b128 minimum, not a fixable skew.

typedef __attribute__((ext_vector_type(8))) short bf16x8;
typedef __attribute__((ext_vector_type(4))) float f32x4;

__device__ __forceinline__ unsigned short f2b(float f) {
    return __builtin_bit_cast(unsigned short, __float2bfloat16(f));
}
__device__ __forceinline__ float b2f(unsigned short s) {
    unsigned u = ((unsigned)s) << 16;
    return __builtin_bit_cast(float, u);
}

// ---- pre-kernel: W0 [4][64][16] -> ws[0..4095]  = wt0[h*16+o][f] (bf16)
//                  W1 [64][64]    -> ws[4096..]   = wt1[o][f]      (bf16)
__global__ __launch_bounds__(256) void prep_weights(
    const float* __restrict__ w0g, const float* __restrict__ w1g,
    unsigned short* __restrict__ ws)
{
    const int tid = threadIdx.x;
    #pragma unroll
    for (int k = 0; k < 16; ++k) {
        int idx = k * 256 + tid;
        int hh = idx >> 10, f = (idx >> 4) & 63, o = idx & 15;
        ws[(hh * 16 + o) * 64 + f] = f2b(w0g[idx]);
        int f1 = idx >> 6, o1 = idx & 63;
        ws[4096 + o1 * 64 + f1] = f2b(w1g[idx]);
    }
}

__global__ __launch_bounds__(256, 5) void gat_fused(
    const float* __restrict__ x, const int* __restrict__ fhi,
    const unsigned short* __restrict__ wsb,   // prepped bf16 weights
    const float* __restrict__ as0, const float* __restrict__ ad0,
    const float* __restrict__ b0g,
    const float* __restrict__ as1, const float* __restrict__ ad1,
    const float* __restrict__ b1g,
    float* __restrict__ out)
{
    const int b = blockIdx.x;
    const int scene = b >> 3;
    const int tt = b & 7;
    const int tid = threadIdx.x;
    const int lane = tid & 63;
    const int wv = tid >> 6;
    const int lg = lane >> 4;
    const int li = lane & 15;
    constexpr float L2E = 1.44269504f;

    __shared__ __align__(16) unsigned short hb [64][72];   // 9216 B
    __shared__ __align__(16) unsigned short wt [64][72];   // 9216 B
    __shared__ __align__(16) unsigned short hpt[64][72];   // 9216 B
    __shared__ float sd[8][64];     // sarr[0..3]/darr[0..3]  ALIAS norm red[0..7]
    __shared__ float denv[4][64];
    __shared__ float maskv[64], asv[64], adv[64], b1v[64], b0v[16];
    float* const sarr = &sd[0][0];  // sd[h]   = sarr[h]
    float* const darr = &sd[4][0];  // sd[4+h] = darr[h]

    // ---------------- stage x (bf16), W0 (prepped), small vectors ----------------
    {
        const float* xb = x + (size_t)b * 4096;
        #pragma unroll
        for (int k = 0; k < 4; ++k) {
            int idx = (k * 256 + tid) * 4;
            float4 v = *(const float4*)(xb + idx);
            ushort4 bv;
            bv.x = f2b(v.x); bv.y = f2b(v.y); bv.z = f2b(v.z); bv.w = f2b(v.w);
            *(ushort4*)&hb[idx >> 6][idx & 63] = bv;
        }
        #pragma unroll
        for (int k = 0; k < 2; ++k) {
            int idx = (k * 256 + tid) * 8;           // 4096 bf16 = 2 passes
            *(uint4*)&wt[idx >> 6][idx & 63] = *(const uint4*)(wsb + idx);
        }
        if (tid < 64) {
            maskv[tid] = (fhi[scene * 64 + tid] <= tt) ? 1.0f : 0.0f;
            asv[tid] = as0[tid];
            adv[tid] = ad0[tid];
            b1v[tid] = b1g[tid];
            if (tid < 16) b0v[tid] = b0g[tid];
        }
    }
    __syncthreads();

    float invcnt = 0.f;
    if (tid < 64) {
        float c = 0.f;
        #pragma unroll
        for (int m = 0; m < 64; ++m) c += maskv[m];
        invcnt = 1.0f / fmaxf(c, 1.0f);
    }

    // ---------------- masked instance norm (bf16 in/out, fp32 stats) --------
    auto do_norm = [&]() {
        float s = 0.f, q = 0.f;
        #pragma unroll
        for (int k = 0; k < 16; ++k) {
            int r = k * 4 + wv;
            float xv = b2f(hb[r][lane]);
            float xm = xv * maskv[r];
            s += xm;
            q = fmaf(xm, xv, q);
        }
        sd[wv][lane] = s;
        sd[4 + wv][lane] = q;
        __syncthreads();
        if (tid < 64) {
            float sum = sd[0][tid] + sd[1][tid] + sd[2][tid] + sd[3][tid];
            float ssq = sd[4][tid] + sd[5][tid] + sd[6][tid] + sd[7][tid];
            float mean = sum * invcnt;
            float var = fmaxf(ssq * invcnt - mean * mean, 0.f);
            sd[0][tid] = mean;
            sd[1][tid] = rsqrtf(var + 1e-5f);
        }
        __syncthreads();
        {
            float mean = sd[0][lane], rstd = sd[1][lane];
            #pragma unroll
            for (int k = 0; k < 16; ++k) {
                int r = k * 4 + wv;
                hb[r][lane] = f2b((b2f(hb[r][lane]) - mean) * rstd);
            }
        }
        __syncthreads();
    };

    // ---------------- hp = h @ W via MFMA; write hp^T bf16 ----------------
    auto do_matmul = [&]() {
        const unsigned short* arow = &hb[16 * wv + li][0];
        bf16x8 a0 = *(const bf16x8*)(arow + 8 * lg);
        bf16x8 a1 = *(const bf16x8*)(arow + 32 + 8 * lg);
        #pragma unroll
        for (int c = 0; c < 4; ++c) {
            const unsigned short* brow = &wt[16 * c + li][0];
            bf16x8 bv0 = *(const bf16x8*)(brow + 8 * lg);
            bf16x8 bv1 = *(const bf16x8*)(brow + 32 + 8 * lg);
            f32x4 acc = {0.f, 0.f, 0.f, 0.f};
            acc = __builtin_amdgcn_mfma_f32_16x16x32_bf16(a0, bv0, acc, 0, 0, 0);
            acc = __builtin_amdgcn_mfma_f32_16x16x32_bf16(a1, bv1, acc, 0, 0, 0);
            ushort4 pv;
            pv.x = f2b(acc[0]); pv.y = f2b(acc[1]);
            pv.z = f2b(acc[2]); pv.w = f2b(acc[3]);
            *(ushort4*)&hpt[16 * c + li][16 * wv + 4 * lg] = pv;
        }
        __syncthreads();
    };

    // --------- P (in-register, A-layout, exp2 pre-scaled) + aggregate MFMA -------
    auto do_attn = [&](int layer) {
        const int row = 16 * wv + li;
        const float mymask = maskv[row];
        const float base = 1.0f - mymask;
        const f32x4 zero = {0.f, 0.f, 0.f, 0.f};
        f32x4 C0 = zero, C1 = zero, C2 = zero, C3 = zero;
        float den[4] = {0.f, 0.f, 0.f, 0.f};

        if (layer == 0) {
            float sh[4];
            #pragma unroll
            for (int h = 0; h < 4; ++h) sh[h] = sarr[h * 64 + row];
            #pragma unroll
            for (int t = 0; t < 2; ++t) {
                const int mb = 32 * t + 8 * lg;
                #pragma unroll
                for (int h = 0; h < 4; ++h) {
                    bf16x8 a;
                    #pragma unroll
                    for (int j = 0; j < 8; ++j) {
                        float v = sh[h] + darr[h * 64 + mb + j];  // log2-domain
                        v = fmaxf(v, 0.2f * v);                   // leaky relu
                        float e = fmaf(exp2f(v), mymask, base);
                        den[h] += e;
                        a[j] = (short)f2b(e);
                    }
                    bf16x8 bv = *(const bf16x8*)&hpt[16 * h + li][mb];
                    if (h == 0) C0 = __builtin_amdgcn_mfma_f32_16x16x32_bf16(a, bv, C0, 0, 0, 0);
                    if (h == 1) C1 = __builtin_amdgcn_mfma_f32_16x16x32_bf16(a, bv, C1, 0, 0, 0);
                    if (h == 2) C2 = __builtin_amdgcn_mfma_f32_16x16x32_bf16(a, bv, C2, 0, 0, 0);
                    if (h == 3) C3 = __builtin_amdgcn_mfma_f32_16x16x32_bf16(a, bv, C3, 0, 0, 0);
                }
            }
            #pragma unroll
            for (int h = 0; h < 4; ++h) {
                float d = den[h];
                d += __shfl_xor(d, 16);
                d += __shfl_xor(d, 32);
                denv[h][row] = 1.0f / d;
            }
            const int n0 = 16 * wv + 4 * lg;
            #pragma unroll
            for (int c = 0; c < 4; ++c) {
                f32x4 C = (c == 0) ? C0 : (c == 1) ? C1 : (c == 2) ? C2 : C3;
                float bias = b0v[li];
                #pragma unroll
                for (int r = 0; r < 4; ++r) {
                    float val = fmaf(C[r], denv[c][n0 + r], bias);
                    val = (val > 0.f) ? val : (__expf(val) - 1.0f);   // ELU
                    hb[n0 + r][16 * c + li] = f2b(val);
                }
            }
            __syncthreads();
        } else {
            const float s0 = sarr[row];
            #pragma unroll
            for (int t = 0; t < 2; ++t) {
                const int mb = 32 * t + 8 * lg;
                bf16x8 a;
                #pragma unroll
                for (int j = 0; j < 8; ++j) {
                    float v = s0 + darr[mb + j];
                    v = fmaxf(v, 0.2f * v);
                    float e = fmaf(exp2f(v), mymask, base);
                    den[0] += e;
                    a[j] = (short)f2b(e);
                }
                bf16x8 bv0 = *(const bf16x8*)&hpt[li][mb];
                bf16x8 bv1 = *(const bf16x8*)&hpt[16 + li][mb];
                bf16x8 bv2 = *(const bf16x8*)&hpt[32 + li][mb];
                bf16x8 bv3 = *(const bf16x8*)&hpt[48 + li][mb];
                C0 = __builtin_amdgcn_mfma_f32_16x16x32_bf16(a, bv0, C0, 0, 0, 0);
                C1 = __builtin_amdgcn_mfma_f32_16x16x32_bf16(a, bv1, C1, 0, 0, 0);
                C2 = __builtin_amdgcn_mfma_f32_16x16x32_bf16(a, bv2, C2, 0, 0, 0);
                C3 = __builtin_amdgcn_mfma_f32_16x16x32_bf16(a, bv3, C3, 0, 0, 0);
            }
            {
                float d = den[0];
                d += __shfl_xor(d, 16);
                d += __shfl_xor(d, 32);
                denv[0][row] = 1.0f / d;
            }
            const int n0 = 16 * wv + 4 * lg;
            float* ob = out + (size_t)b * 4096;
            #pragma unroll
            for (int c = 0; c < 4; ++c) {
                f32x4 C = (c == 0) ? C0 : (c == 1) ? C1 : (c == 2) ? C2 : C3;
                float bias = b1v[16 * c + li];
                #pragma unroll
                for (int r = 0; r < 4; ++r) {
                    float val = fmaf(C[r], denv[0][n0 + r], bias);
                    ob[(n0 + r) * 64 + 16 * c + li] = val;
                }
            }
        }
    };

    // ================= layer 0 =================
    do_norm();
    do_matmul();
    {   // per-head scores; pre-scale by log2e, clamp 63 (guards garbage rows)
        float sv = 0.f, dv = 0.f;
        #pragma unroll
        for (int o = 0; o < 16; ++o) {
            float v = b2f(hpt[16 * wv + o][lane]);
            sv = fmaf(v, asv[16 * wv + o], sv);
            dv = fmaf(v, adv[16 * wv + o], dv);
        }
        sarr[wv * 64 + lane] = fminf(sv * L2E, 63.f);
        darr[wv * 64 + lane] = (maskv[lane] > 0.f) ? fminf(dv * L2E, 63.f) : -1e30f;
    }
    // stage W1 (prepped) now; wt dead until matmul1
    #pragma unroll
    for (int k = 0; k < 2; ++k) {
        int idx = (k * 256 + tid) * 8;
        *(uint4*)&wt[idx >> 6][idx & 63] = *(const uint4*)(wsb + 4096 + idx);
    }
    __syncthreads();
    if (tid < 64) { asv[tid] = as1[tid]; adv[tid] = ad1[tid]; }
    do_attn(0);

    // ================= layer 1 =================
    do_norm();
    do_matmul();
    if (tid < 128) {   // single head: wave0 -> s, wave1 -> d
        float acc = 0.f;
        const float* av = (tid < 64) ? asv : adv;
        #pragma unroll 8
        for (int o = 0; o < 64; ++o)
            acc = fmaf(b2f(hpt[o][lane]), av[o], acc);
        if (tid < 64) sarr[lane] = fminf(acc * L2E, 63.f);
        else          darr[lane] = (maskv[lane] > 0.f) ? fminf(acc * L2E, 63.f) : -1e30f;
    }
    __syncthreads();
    do_attn(1);
}

extern "C" void kernel_launch(void* const* d_in, const int* in_sizes, int n_in,
                              void* d_out, int out_size, void* d_ws, size_t ws_size,
                              hipStream_t stream)
{
    const float* x   = (const float*)d_in[0];
    const int*   fhi = (const int*)d_in[1];
    const float* w0  = (const float*)d_in[2];
    const float* as0 = (const float*)d_in[3];
    const float* ad0 = (const float*)d_in[4];
    const float* b0  = (const float*)d_in[5];
    const float* w1  = (const float*)d_in[6];
    const float* as1 = (const float*)d_in[7];
    const float* ad1 = (const float*)d_in[8];
    const float* b1  = (const float*)d_in[9];
    float* o = (float*)d_out;
    unsigned short* ws = (unsigned short*)d_ws;
    hipLaunchKernelGGL(prep_weights, dim3(1), dim3(256), 0, stream, w0, w1, ws);
    hipLaunchKernelGGL(gat_fused, dim3(8192), dim3(256), 0, stream,
                       x, fhi, ws, as0, ad0, b0, as1, ad1, b1, o);
}